// Round 1
// 232.472 us; speedup vs baseline: 1.0141x; 1.0141x over previous
//
#include <hip/hip_runtime.h>

#define B_   2
#define NC_  256
#define CN_  256
#define K_   16
#define DN_  64
#define G_   8
#define HM_  128
#define F3_  192

typedef unsigned short u16;
typedef short v8s __attribute__((ext_vector_type(8)));
typedef float v4f __attribute__((ext_vector_type(4)));

// LDS layout (bytes):
//   hT   @ 0       : [64][272] bf16 = 34816   (h transposed, persistent; gather B-operand)
//   big  @ 34816   : [256][136] bf16 = 69632  (Wg[64][272] during gather; then mh; then sh)
//   am   @ 104448  : [256][72]  bf16 = 36864  (agg bf16, then msg bf16 for s1 A-frags)
//   ctxl @ 141312  : [64] bf16 = 128
//   hsum @ 141440  : [16][64] f32 = 4096      (per (wave,quad) partial col-sums of h_new;
//                                              reused as ph partials in mod tail)
//   msum @ 145536  : [16][64] f32 = 4096      (same for msg)
//   pool @ 149632  : [128] f32 = 512          (pooled stats for mod MLP)
#define SMEM_BYTES 150144

// d_ws layout: bf16 weight copies
//   mw1b @ u16[0]       (196608)   mw2b @ u16[196608] (65536)
//   sw1b @ u16[262144]  (196608)   sw2b @ u16[458752] (65536)

__device__ __forceinline__ u16 f2b(float f) {
    unsigned v; __builtin_memcpy(&v, &f, 4);
    v = v + 0x7fffu + ((v >> 16) & 1u);   // RNE
    return (u16)(v >> 16);
}
__device__ __forceinline__ v8s cvt8(const float* p) {
    float4 a = *(const float4*)p, b = *(const float4*)(p + 4);
    v8s r;
    r[0] = (short)f2b(a.x); r[1] = (short)f2b(a.y); r[2] = (short)f2b(a.z); r[3] = (short)f2b(a.w);
    r[4] = (short)f2b(b.x); r[5] = (short)f2b(b.y); r[6] = (short)f2b(b.z); r[7] = (short)f2b(b.w);
    return r;
}
__device__ __forceinline__ float gelu_t(float x) {
    // jax.nn.gelu approximate=True: x*sigmoid(2*k0*x*(1+k1*x^2))
    float u = x * x;
    float t = 1.5957691216057308f * x * __builtin_fmaf(0.044715f, u, 1.0f);
    float e = __expf(-t);
    return x * __builtin_amdgcn_rcpf(1.0f + e);
}

__global__ __launch_bounds__(256) void cvt_w(
    const float* __restrict__ mw1, const float* __restrict__ mw2,
    const float* __restrict__ sw1, const float* __restrict__ sw2,
    u16* __restrict__ dst)
{
    int e = (blockIdx.x * 256 + threadIdx.x) * 4;   // 131072 threads * 4 = 524288
    const float* s; int off;
    if      (e < 196608) { s = mw1; off = e; }
    else if (e < 262144) { s = mw2; off = e - 196608; }
    else if (e < 458752) { s = sw1; off = e - 262144; }
    else                 { s = sw2; off = e - 458752; }
    float4 v = *(const float4*)(s + off);
    ushort4 o4;
    o4.x = f2b(v.x); o4.y = f2b(v.y); o4.z = f2b(v.z); o4.w = f2b(v.w);
    *(ushort4*)(dst + e) = o4;
}

__global__ __launch_bounds__(256) void mg_main(
    const float* __restrict__ h,    const float* __restrict__ wconn,
    const float* __restrict__ ctx,  const float* __restrict__ nid,
    const u16* __restrict__ mw1b,   const float* __restrict__ mb1,
    const u16* __restrict__ mw2b,   const float* __restrict__ mb2,
    const u16* __restrict__ sw1b,   const float* __restrict__ sb1,
    const u16* __restrict__ sw2b,   const float* __restrict__ sb2,
    const int* __restrict__ conn,   const int* __restrict__ c2g,
    const float* __restrict__ dw1,  const float* __restrict__ db1,
    const float* __restrict__ dw2,  const float* __restrict__ db2,
    float* __restrict__ outf)
{
    const int bn   = blockIdx.x;
    const int n    = bn & 255;
    const int tid  = threadIdx.x;
    const int wave = tid >> 6;
    const int lane = tid & 63;
    const int q    = lane >> 4;
    const int ln   = lane & 15;
    const int g    = c2g[n];

    extern __shared__ char smem[];
    u16*   hT   = (u16*)(smem);
    u16*   big  = (u16*)(smem + 34816);
    u16*   wg   = big;
    u16*   am   = (u16*)(smem + 104448);
    u16*   ctxl = (u16*)(smem + 141312);
    float* hsum = (float*)(smem + 141440);   // [16][64]: slot (wave*4+q)*64+col
    float* msum = (float*)(smem + 145536);
    float* pool = (float*)(smem + 149632);   // [128] pooled stats

    const size_t hbase = (size_t)bn * (CN_ * DN_);
    const size_t nbase = (size_t)n  * (CN_ * DN_);
    float* oH = outf + (size_t)bn * 16384;
    float* oM = outf + (size_t)8388608 + (size_t)bn * 16384;

    // ---------------- phase 0: ctx (f32->bf16) + hT transpose ----------------
    if (tid < 64) ctxl[tid] = f2b(ctx[(size_t)bn * DN_ + tid]);
    {
        const float* hrow = h + hbase + (size_t)tid * DN_;
#pragma unroll
        for (int i = 0; i < 16; ++i) {
            float4 v = *(const float4*)(hrow + i * 4);
            hT[(i * 4 + 0) * 272 + tid] = f2b(v.x);
            hT[(i * 4 + 1) * 272 + tid] = f2b(v.y);
            hT[(i * 4 + 2) * 272 + tid] = f2b(v.z);
            hT[(i * 4 + 3) * 272 + tid] = f2b(v.w);
        }
    }
    __syncthreads();

    // ---------------- gather: agg = denseW @ h via MFMA, 4 strips -------------
    for (int s = 0; s < 4; ++s) {
#pragma unroll
        for (int i = 0; i < 9; ++i) {
            int idx = tid + i * 256;
            if (idx < 2176) ((uint4*)wg)[idx] = make_uint4(0u, 0u, 0u, 0u);
        }
        __syncthreads();
#pragma unroll
        for (int i = 0; i < 4; ++i) {
            int p  = i * 256 + tid;             // p in [0,1024)
            int cl = p >> 4;                    // local row
            int iv = conn[n * 4096 + s * 1024 + p];
            float wv = wconn[(size_t)bn * 4096 + s * 1024 + p];
            wg[cl * 272 + iv] = f2b(wv);
        }
        __syncthreads();
        {
            v4f a0 = {0,0,0,0}, a1 = {0,0,0,0}, a2 = {0,0,0,0}, a3 = {0,0,0,0};
            const u16* arow = wg + (wave * 16 + ln) * 272 + q * 8;
#pragma unroll
            for (int ks = 0; ks < 8; ++ks) {
                v8s a   = *(const v8s*)(arow + ks * 32);
                v8s bb0 = *(const v8s*)(hT + ( 0 + ln) * 272 + ks * 32 + q * 8);
                v8s bb1 = *(const v8s*)(hT + (16 + ln) * 272 + ks * 32 + q * 8);
                v8s bb2 = *(const v8s*)(hT + (32 + ln) * 272 + ks * 32 + q * 8);
                v8s bb3 = *(const v8s*)(hT + (48 + ln) * 272 + ks * 32 + q * 8);
                a0 = __builtin_amdgcn_mfma_f32_16x16x32_bf16(a, bb0, a0, 0, 0, 0);
                a1 = __builtin_amdgcn_mfma_f32_16x16x32_bf16(a, bb1, a1, 0, 0, 0);
                a2 = __builtin_amdgcn_mfma_f32_16x16x32_bf16(a, bb2, a2, 0, 0, 0);
                a3 = __builtin_amdgcn_mfma_f32_16x16x32_bf16(a, bb3, a3, 0, 0, 0);
            }
            int crow = s * 64 + wave * 16 + q * 4;
#pragma unroll
            for (int r = 0; r < 4; ++r) {
                am[(crow + r) * 72 +  0 + ln] = f2b(a0[r]);
                am[(crow + r) * 72 + 16 + ln] = f2b(a1[r]);
                am[(crow + r) * 72 + 32 + ln] = f2b(a2[r]);
                am[(crow + r) * 72 + 48 + ln] = f2b(a3[r]);
            }
        }
        __syncthreads();
    }

    const int cbase = wave * 64;   // wave-private rows; MLP chain barrier-free

    // ---------------- m1: mh = gelu([h|agg|nid] @ mw1^T + mb1) ---------------
    {
        v8s afr[4][6];
#pragma unroll
        for (int mi = 0; mi < 4; ++mi) {
            int c = cbase + mi * 16 + ln;
            afr[mi][0] = cvt8(h + hbase + (size_t)c * 64 +  0 + q * 8);
            afr[mi][1] = cvt8(h + hbase + (size_t)c * 64 + 32 + q * 8);
            afr[mi][2] = *(const v8s*)(am + c * 72 +  0 + q * 8);
            afr[mi][3] = *(const v8s*)(am + c * 72 + 32 + q * 8);
            afr[mi][4] = cvt8(nid + nbase + (size_t)c * 64 +  0 + q * 8);
            afr[mi][5] = cvt8(nid + nbase + (size_t)c * 64 + 32 + q * 8);
        }
        float b1v[8];
#pragma unroll
        for (int nt = 0; nt < 8; ++nt) b1v[nt] = mb1[g * HM_ + nt * 16 + ln];
        const u16* w1g = mw1b + (size_t)g * HM_ * F3_;
#pragma unroll
        for (int nt = 0; nt < 8; ++nt) {
            v4f acc[4] = {{0,0,0,0},{0,0,0,0},{0,0,0,0},{0,0,0,0}};
#pragma unroll
            for (int ks = 0; ks < 6; ++ks) {
                v8s bf = *(const v8s*)(w1g + (nt * 16 + ln) * F3_ + ks * 32 + q * 8);
#pragma unroll
                for (int mi = 0; mi < 4; ++mi)
                    acc[mi] = __builtin_amdgcn_mfma_f32_16x16x32_bf16(afr[mi][ks], bf, acc[mi], 0, 0, 0);
            }
#pragma unroll
            for (int mi = 0; mi < 4; ++mi) {
                int c = cbase + mi * 16 + q * 4;
#pragma unroll
                for (int r = 0; r < 4; ++r)
                    big[(c + r) * 136 + nt * 16 + ln] = f2b(gelu_t(acc[mi][r] + b1v[nt]));
            }
        }
    }

    // ---------------- m2: msg = mh @ mw2^T + mb2  (am bf16 + global f32) -----
    {
        v8s afr[4][4];
#pragma unroll
        for (int mi = 0; mi < 4; ++mi) {
            int c = cbase + mi * 16 + ln;
#pragma unroll
            for (int ks = 0; ks < 4; ++ks)
                afr[mi][ks] = *(const v8s*)(big + c * 136 + ks * 32 + q * 8);
        }
        const u16* w2g = mw2b + (size_t)g * DN_ * HM_;
        float mpart[4];
#pragma unroll
        for (int nt = 0; nt < 4; ++nt) {
            float bb = mb2[g * DN_ + nt * 16 + ln];
            v4f acc[4] = {{0,0,0,0},{0,0,0,0},{0,0,0,0},{0,0,0,0}};
#pragma unroll
            for (int ks = 0; ks < 4; ++ks) {
                v8s bf = *(const v8s*)(w2g + (nt * 16 + ln) * HM_ + ks * 32 + q * 8);
#pragma unroll
                for (int mi = 0; mi < 4; ++mi)
                    acc[mi] = __builtin_amdgcn_mfma_f32_16x16x32_bf16(afr[mi][ks], bf, acc[mi], 0, 0, 0);
            }
            float ms = 0.0f;
            int d = nt * 16 + ln;
#pragma unroll
            for (int mi = 0; mi < 4; ++mi) {
                int c = cbase + mi * 16 + q * 4;
#pragma unroll
                for (int r = 0; r < 4; ++r) {
                    float mv = acc[mi][r] + bb;
                    am[(c + r) * 72 + d] = f2b(mv);
                    oM[(size_t)(c + r) * 64 + d] = mv;
                    ms += mv;
                }
            }
            mpart[nt] = ms;
        }
#pragma unroll
        for (int nt = 0; nt < 4; ++nt)
            msum[(wave * 4 + q) * 64 + nt * 16 + ln] = mpart[nt];
    }

    // ---------------- s1: sh = gelu([h|msg|ctx] @ sw1^T + sb1) ---------------
    {
        v8s cfr0 = *(const v8s*)(ctxl +  0 + q * 8);
        v8s cfr1 = *(const v8s*)(ctxl + 32 + q * 8);
        v8s afr[4][4];
#pragma unroll
        for (int mi = 0; mi < 4; ++mi) {
            int c = cbase + mi * 16 + ln;
            afr[mi][0] = cvt8(h + hbase + (size_t)c * 64 +  0 + q * 8);
            afr[mi][1] = cvt8(h + hbase + (size_t)c * 64 + 32 + q * 8);
            afr[mi][2] = *(const v8s*)(am + c * 72 +  0 + q * 8);
            afr[mi][3] = *(const v8s*)(am + c * 72 + 32 + q * 8);
        }
        float b1v[8];
#pragma unroll
        for (int nt = 0; nt < 8; ++nt) b1v[nt] = sb1[g * HM_ + nt * 16 + ln];
        const u16* w1g = sw1b + (size_t)g * HM_ * F3_;
#pragma unroll
        for (int nt = 0; nt < 8; ++nt) {
            v4f acc[4] = {{0,0,0,0},{0,0,0,0},{0,0,0,0},{0,0,0,0}};
#pragma unroll
            for (int ks = 0; ks < 4; ++ks) {
                v8s bf = *(const v8s*)(w1g + (nt * 16 + ln) * F3_ + ks * 32 + q * 8);
#pragma unroll
                for (int mi = 0; mi < 4; ++mi)
                    acc[mi] = __builtin_amdgcn_mfma_f32_16x16x32_bf16(afr[mi][ks], bf, acc[mi], 0, 0, 0);
            }
#pragma unroll
            for (int ks = 4; ks < 6; ++ks) {
                v8s bf = *(const v8s*)(w1g + (nt * 16 + ln) * F3_ + ks * 32 + q * 8);
                v8s aa = (ks == 4) ? cfr0 : cfr1;   // ctx broadcast across rows
#pragma unroll
                for (int mi = 0; mi < 4; ++mi)
                    acc[mi] = __builtin_amdgcn_mfma_f32_16x16x32_bf16(aa, bf, acc[mi], 0, 0, 0);
            }
#pragma unroll
            for (int mi = 0; mi < 4; ++mi) {
                int c = cbase + mi * 16 + q * 4;
#pragma unroll
                for (int r = 0; r < 4; ++r)
                    big[(c + r) * 136 + nt * 16 + ln] = f2b(gelu_t(acc[mi][r] + b1v[nt]));
            }
        }
    }

    // ---------------- s2: h_new = h(f32) + sh @ sw2^T + sb2  (global f32) ----
    {
        v8s afr[4][4];
#pragma unroll
        for (int mi = 0; mi < 4; ++mi) {
            int c = cbase + mi * 16 + ln;
#pragma unroll
            for (int ks = 0; ks < 4; ++ks)
                afr[mi][ks] = *(const v8s*)(big + c * 136 + ks * 32 + q * 8);
        }
        const u16* w2g = sw2b + (size_t)g * DN_ * HM_;
        float hpart[4];
#pragma unroll
        for (int nt = 0; nt < 4; ++nt) {
            float bb = sb2[g * DN_ + nt * 16 + ln];
            v4f acc[4] = {{0,0,0,0},{0,0,0,0},{0,0,0,0},{0,0,0,0}};
#pragma unroll
            for (int ks = 0; ks < 4; ++ks) {
                v8s bf = *(const v8s*)(w2g + (nt * 16 + ln) * HM_ + ks * 32 + q * 8);
#pragma unroll
                for (int mi = 0; mi < 4; ++mi)
                    acc[mi] = __builtin_amdgcn_mfma_f32_16x16x32_bf16(afr[mi][ks], bf, acc[mi], 0, 0, 0);
            }
            float hs = 0.0f;
            int d = nt * 16 + ln;
#pragma unroll
            for (int mi = 0; mi < 4; ++mi) {
                int c = cbase + mi * 16 + q * 4;
#pragma unroll
                for (int r = 0; r < 4; ++r) {
                    float hv = h[hbase + (size_t)(c + r) * 64 + d];   // f32 residual
                    float hn = hv + acc[mi][r] + bb;
                    oH[(size_t)(c + r) * 64 + d] = hn;
                    hs += hn;
                }
            }
            hpart[nt] = hs;
        }
#pragma unroll
        for (int nt = 0; nt < 4; ++nt)
            hsum[(wave * 4 + q) * 64 + nt * 16 + ln] = hpart[nt];
    }
    __syncthreads();

    // ---------------- pooled means (f32) into LDS ----------------------------
    if (tid < 128) {
        int col = tid & 63;
        const float* src = (tid < 64) ? hsum : msum;
        float s = 0.0f;
#pragma unroll
        for (int i = 0; i < 16; ++i) s += src[i * 64 + col];
        pool[tid] = s * (1.0f / 256.0f);
    }
    __syncthreads();

    // ---------------- mod MLP layer 1 (fused; was mg_mod) --------------------
    // 4-way f-split: wave w handles f in [w*32, w*32+32), col = lane (coalesced).
    {
        const int col = tid & 63, fh = tid >> 6;
        const float* w1p = dw1 + ((size_t)n * 128 + fh * 32) * 64 + col;
        const float* pv  = pool + fh * 32;
        float acc = 0.0f;
#pragma unroll
        for (int f = 0; f < 32; ++f)
            acc = __builtin_fmaf(pv[f], w1p[(size_t)f * 64], acc);
        hsum[fh * 64 + col] = acc;   // hsum reused as ph partials (dead after pooled)
    }
    __syncthreads();

    // ---------------- mod MLP layer 2 + output -------------------------------
    if (tid < 64) {
        float a  = hsum[tid] + hsum[64 + tid] + hsum[128 + tid] + hsum[192 + tid]
                 + db1[n * 64 + tid];
        float ph = gelu_t(a);
        float part[5];
#pragma unroll
        for (int o = 0; o < 5; ++o) part[o] = ph * dw2[((size_t)n * 64 + tid) * 5 + o];
#pragma unroll
        for (int off = 32; off > 0; off >>= 1)
#pragma unroll
            for (int o = 0; o < 5; ++o) part[o] += __shfl_down(part[o], off);
        if (tid == 0) {
#pragma unroll
            for (int o = 0; o < 5; ++o)
                outf[(size_t)16777216 + bn * 5 + o] = part[o] + db2[n * 5 + o];
        }
    }
}

extern "C" void kernel_launch(void* const* d_in, const int* in_sizes, int n_in,
                              void* d_out, int out_size, void* d_ws, size_t ws_size,
                              hipStream_t stream) {
    const float* h     = (const float*)d_in[0];
    const float* wconn = (const float*)d_in[1];
    const float* ctx   = (const float*)d_in[2];
    const float* nid   = (const float*)d_in[3];
    const float* mw1   = (const float*)d_in[4];
    const float* mb1   = (const float*)d_in[5];
    const float* mw2   = (const float*)d_in[6];
    const float* mb2   = (const float*)d_in[7];
    const float* sw1   = (const float*)d_in[8];
    const float* sb1   = (const float*)d_in[9];
    const float* sw2   = (const float*)d_in[10];
    const float* sb2   = (const float*)d_in[11];
    const float* dw1   = (const float*)d_in[12];
    const float* db1   = (const float*)d_in[13];
    const float* dw2   = (const float*)d_in[14];
    const float* db2   = (const float*)d_in[15];
    const int* conn    = (const int*)d_in[16];
    const int* c2g     = (const int*)d_in[17];
    float* outf  = (float*)d_out;
    u16*   wb    = (u16*)d_ws;                        // bf16 weight copies

    hipFuncSetAttribute(reinterpret_cast<const void*>(&mg_main),
                        hipFuncAttributeMaxDynamicSharedMemorySize, SMEM_BYTES);

    cvt_w<<<512, 256, 0, stream>>>(mw1, mw2, sw1, sw2, wb);
    mg_main<<<512, 256, SMEM_BYTES, stream>>>(h, wconn, ctx, nid,
                                              wb,           mb1,
                                              wb + 196608,  mb2,
                                              wb + 262144,  sb1,
                                              wb + 458752,  sb2,
                                              conn, c2g,
                                              dw1, db1, dw2, db2,
                                              outf);
}